// Round 1
// baseline (222.781 us; speedup 1.0000x reference)
//
#include <hip/hip_runtime.h>
#include <hip/hip_bf16.h>
#include <cstdint>
#include <cstddef>

// Problem constants
#define L_SER 4096   // series length (L)
#define DEMB  1024   // d_emb
#define DV    1024   // d_v
// H = HURST - 0.5 = 0.2 ; dt = 1/4096 ; eps = 1e-8

typedef __bf16 bf16_t;
typedef __attribute__((ext_vector_type(8))) __bf16 bf16x8;
typedef __attribute__((ext_vector_type(4))) float f32x4;

// ---------------------------------------------------------------------------
// a[d] = (d*dt + 1e-8)^0.2 for d>=1 ; a[0] = (1e-8)^0.2
// A2[i,j] = a[i-j] for i>=j else 0  (lower-triangular Toeplitz)
// ---------------------------------------------------------------------------
__global__ void build_a_kernel(bf16_t* __restrict__ av) {
    int d = blockIdx.x * blockDim.x + threadIdx.x;
    if (d < L_SER) {
        float base = (d == 0) ? 1e-8f : ((float)d * (1.0f / (float)L_SER) + 1e-8f);
        av[d] = (bf16_t)powf(base, 0.2f);
    }
}

__global__ void conv_w_kernel(const float* __restrict__ W, bf16_t* __restrict__ Wb) {
    int i = blockIdx.x * blockDim.x + threadIdx.x;
    if (i < DV * DEMB) Wb[i] = (bf16_t)W[i];
}

// E is (d_emb, L) row-major; produce Et (L, d_emb) bf16 so GEMM1's B-operand
// (needs 8 consecutive e at fixed l) is contiguous.
__global__ void transpose_e_kernel(const float* __restrict__ E, bf16_t* __restrict__ Et) {
    __shared__ float tile[32][33];
    int l0 = blockIdx.x * 32;
    int e0 = blockIdx.y * 32;
    int tx = threadIdx.x, ty = threadIdx.y;
#pragma unroll
    for (int i = 0; i < 32; i += 8)
        tile[ty + i][tx] = E[(size_t)(e0 + ty + i) * L_SER + l0 + tx];
    __syncthreads();
#pragma unroll
    for (int i = 0; i < 32; i += 8)
        Et[(size_t)(l0 + ty + i) * DEMB + e0 + tx] = (bf16_t)tile[tx][ty + i];
}

// ---------------------------------------------------------------------------
// GEMM1: Yt[v, l] = sum_e W[v,e] * E[e,l]   (M=DV over v, N=L over l, K=DEMB)
//   A[m=v][k=e] = Wb[v][e]  (row-contiguous in e)
//   B[k=e][n=l] = Et[l][e]  (row-contiguous in e)
// 64x64 tile / block, 4 waves, each wave: 4 m-tiles x 1 n-tile of 16x16x32 MFMA.
// ---------------------------------------------------------------------------
__global__ __launch_bounds__(256) void gemm1_kernel(const bf16_t* __restrict__ Wb,
                                                    const bf16_t* __restrict__ Et,
                                                    bf16_t* __restrict__ Yt) {
    __shared__ __align__(16) bf16_t sA[64][40];  // [m=v][k=e], pad to 40 (80B rows, 16B aligned)
    __shared__ __align__(16) bf16_t sB[64][40];  // [n=l][k=e]
    const int v0 = blockIdx.y * 64;
    const int l0 = blockIdx.x * 64;
    const int tid  = threadIdx.x;
    const int wave = tid >> 6;
    const int lane = tid & 63;
    const int quad = lane >> 4;
    const int ln   = lane & 15;
    const int mm = tid >> 2;   // 0..63 staging row
    const int kg = tid & 3;    // 0..3  staging 16B group

    f32x4 acc[4] = {{0,0,0,0},{0,0,0,0},{0,0,0,0},{0,0,0,0}};

    for (int e0 = 0; e0 < DEMB; e0 += 32) {
        __syncthreads();
        *(bf16x8*)&sA[mm][kg * 8] =
            *(const bf16x8*)(Wb + (size_t)(v0 + mm) * DEMB + e0 + kg * 8);
        *(bf16x8*)&sB[mm][kg * 8] =
            *(const bf16x8*)(Et + (size_t)(l0 + mm) * DEMB + e0 + kg * 8);
        __syncthreads();

        bf16x8 bfr = *(const bf16x8*)&sB[wave * 16 + ln][quad * 8];
#pragma unroll
        for (int tm = 0; tm < 4; ++tm) {
            bf16x8 afr = *(const bf16x8*)&sA[tm * 16 + ln][quad * 8];
            acc[tm] = __builtin_amdgcn_mfma_f32_16x16x32_bf16(afr, bfr, acc[tm], 0, 0, 0);
        }
    }

    // C/D layout: col = lane&15, row = quad*4 + r  (m89-verified)
#pragma unroll
    for (int tm = 0; tm < 4; ++tm)
#pragma unroll
        for (int r = 0; r < 4; ++r) {
            int row = v0 + tm * 16 + quad * 4 + r;      // v
            int col = l0 + wave * 16 + ln;              // l
            Yt[(size_t)row * L_SER + col] = (bf16_t)acc[tm][r];
        }
}

// ---------------------------------------------------------------------------
// GEMM2: out[i, v] = sum_{j<=i} a[i-j] * Y[j, v]   (M=L over i, N=DV over v, K=j)
//   A[m=i][k=j] = a[i-j]  (generated into LDS from the 4096-entry a vector)
//   B[k=j][n=v] = Yt[v][j] (row-contiguous in j)
// Triangular skip: K-loop runs only j0 < i0+64.
// ---------------------------------------------------------------------------
__global__ __launch_bounds__(256) void gemm2_kernel(const bf16_t* __restrict__ av,
                                                    const bf16_t* __restrict__ Yt,
                                                    float* __restrict__ out) {
    __shared__ __align__(16) bf16_t sA[64][40];  // [m=i][k=j]
    __shared__ __align__(16) bf16_t sB[64][40];  // [n=v][k=j]
    const int v0 = blockIdx.x * 64;
    const int i0 = blockIdx.y * 64;
    const int tid  = threadIdx.x;
    const int wave = tid >> 6;
    const int lane = tid & 63;
    const int quad = lane >> 4;
    const int ln   = lane & 15;
    const int mm = tid >> 2;
    const int kg = tid & 3;

    f32x4 acc[4] = {{0,0,0,0},{0,0,0,0},{0,0,0,0},{0,0,0,0}};

    const int jend = i0 + 64;  // exclusive; multiples of 32
    for (int j0 = 0; j0 < jend; j0 += 32) {
        __syncthreads();
        // Generate A2 tile from Toeplitz vector: sA[mm][kk] = a[(i0+mm)-(j0+kk)] or 0
#pragma unroll
        for (int u = 0; u < 8; ++u) {
            int kk = kg * 8 + u;
            int idx = (i0 + mm) - (j0 + kk);
            sA[mm][kk] = (idx >= 0) ? av[idx] : (bf16_t)0.0f;
        }
        *(bf16x8*)&sB[mm][kg * 8] =
            *(const bf16x8*)(Yt + (size_t)(v0 + mm) * L_SER + j0 + kg * 8);
        __syncthreads();

        bf16x8 bfr = *(const bf16x8*)&sB[wave * 16 + ln][quad * 8];
#pragma unroll
        for (int tm = 0; tm < 4; ++tm) {
            bf16x8 afr = *(const bf16x8*)&sA[tm * 16 + ln][quad * 8];
            acc[tm] = __builtin_amdgcn_mfma_f32_16x16x32_bf16(afr, bfr, acc[tm], 0, 0, 0);
        }
    }

#pragma unroll
    for (int tm = 0; tm < 4; ++tm)
#pragma unroll
        for (int r = 0; r < 4; ++r) {
            int row = i0 + tm * 16 + quad * 4 + r;      // i
            int col = v0 + wave * 16 + ln;              // v
            out[(size_t)row * DV + col] = acc[tm][r];
        }
}

// ---------------------------------------------------------------------------
extern "C" void kernel_launch(void* const* d_in, const int* in_sizes, int n_in,
                              void* d_out, int out_size, void* d_ws, size_t ws_size,
                              hipStream_t stream) {
    const float* E = (const float*)d_in[0];   // embed_series (1024, 4096) f32
    const float* W = (const float*)d_in[1];   // Wv_weight   (1024, 1024) f32
    float* out = (float*)d_out;               // (4096, 1024) f32

    char* ws = (char*)d_ws;
    bf16_t* Et = (bf16_t*)(ws);                              // 4096*1024*2 = 8 MB
    bf16_t* Wb = (bf16_t*)(ws + (size_t)8  * 1024 * 1024);   // 1024*1024*2 = 2 MB
    bf16_t* Yt = (bf16_t*)(ws + (size_t)10 * 1024 * 1024);   // 1024*4096*2 = 8 MB
    bf16_t* av = (bf16_t*)(ws + (size_t)18 * 1024 * 1024);   // 4096*2 = 8 KB

    build_a_kernel<<<L_SER / 256, 256, 0, stream>>>(av);
    conv_w_kernel<<<(DV * DEMB + 255) / 256, 256, 0, stream>>>(W, Wb);
    transpose_e_kernel<<<dim3(L_SER / 32, DEMB / 32), dim3(32, 8), 0, stream>>>(E, Et);
    gemm1_kernel<<<dim3(L_SER / 64, DV / 64), 256, 0, stream>>>(Wb, Et, Yt);
    gemm2_kernel<<<dim3(DV / 64, L_SER / 64), 256, 0, stream>>>(av, Yt, out);
}

// Round 2
// 162.888 us; speedup vs baseline: 1.3677x; 1.3677x over previous
//
#include <hip/hip_runtime.h>
#include <hip/hip_bf16.h>
#include <cstdint>
#include <cstddef>

// out = A2 @ (E^T @ W^T)  reassociated as  (A2 @ E^T) @ W^T
//   A2[i,j] = a[i-j] (lower-tri Toeplitz), a[d] = (d*dt+1e-8)^0.2, a[0]=1e-8^0.2
//   gemm_a: T[i,e] = sum_{j<=i} a[i-j] * E[e,j]   (M=4096, N=1024, K tri)
//   gemm_b: out[i,v] = sum_e T[i,e] * W[v,e]      (M=4096, N=1024, K=1024)

#define L_SER 4096
#define DEMB  1024
#define DV    1024

#define R_STRIDE 4160   // elements per shift-replica of reversed a (16B-aligned)
#define R_O0     4096

typedef __bf16 bf16_t;
typedef __attribute__((ext_vector_type(8))) __bf16 bf16x8;
typedef __attribute__((ext_vector_type(4))) float f32x4;

__device__ __forceinline__ void load_lds16(const void* g, void* l) {
    __builtin_amdgcn_global_load_lds(
        (const __attribute__((address_space(1))) void*)g,
        (__attribute__((address_space(3))) void*)l, 16, 0, 0);
}

// ---------------------------------------------------------------------------
// R[s][x] = a_val(4096 + s - x) for s in [0,8), x in [0,4160).
// Gives every Toeplitz A-tile row as an aligned, ascending 16B load:
//   row r (global i = i0+r), k-group kc: load R[r&7] at x0 = 4096 - (i0-j0) - 8*(r>>3) + kc
// ---------------------------------------------------------------------------
__global__ void build_r_kernel(bf16_t* __restrict__ R) {
    int idx = blockIdx.x * blockDim.x + threadIdx.x;
    if (idx >= 8 * R_STRIDE) return;
    int s = idx / R_STRIDE;
    int x = idx - s * R_STRIDE;
    int d = R_O0 + s - x;
    float v = 0.0f;
    if (d >= 0 && d < L_SER)
        v = powf((d == 0) ? 1e-8f : ((float)d * (1.0f / (float)L_SER) + 1e-8f), 0.2f);
    R[idx] = (bf16_t)v;
}

// f32 -> bf16 streaming convert, 8 elems/thread (2x float4 in, 1x 16B out)
__global__ void convert_kernel(const float* __restrict__ src, bf16_t* __restrict__ dst, int n8) {
    int idx = blockIdx.x * blockDim.x + threadIdx.x;
    if (idx >= n8) return;
    const f32x4* s = (const f32x4*)src;
    f32x4 v0 = s[idx * 2], v1 = s[idx * 2 + 1];
    bf16x8 o;
    o[0] = (bf16_t)v0[0]; o[1] = (bf16_t)v0[1]; o[2] = (bf16_t)v0[2]; o[3] = (bf16_t)v0[3];
    o[4] = (bf16_t)v1[0]; o[5] = (bf16_t)v1[1]; o[6] = (bf16_t)v1[2]; o[7] = (bf16_t)v1[3];
    ((bf16x8*)dst)[idx] = o;
}

// ---------------------------------------------------------------------------
// gemm_a: T[i,e] = sum_j a[i-j] E[e,j].  BM=64, BN=128, BK=64, triangular K.
// A staged from L1-resident R via global_load_lds; B = Eb rows (j contiguous).
// 4 waves as 2x2; each wave 32(m) x 64(n) = 2x4 MFMA tiles; 16 MFMA / K-step.
// ---------------------------------------------------------------------------
__global__ __launch_bounds__(256) void gemm_a_kernel(const bf16_t* __restrict__ R,
                                                     const bf16_t* __restrict__ Eb,
                                                     bf16_t* __restrict__ T) {
    __shared__ __align__(16) bf16_t sA[64 * 64];    // [m][k] 8 KB, unpadded (global_load_lds)
    __shared__ __align__(16) bf16_t sB[128 * 64];   // [n][k] 16 KB

    const int bid   = blockIdx.x;          // LPT: biggest i-blocks first
    const int i_blk = 63 - (bid >> 3);
    const int n_blk = bid & 7;
    const int i0 = i_blk * 64;
    const int n0 = n_blk * 128;

    const int tid  = threadIdx.x;
    const int wave = tid >> 6;
    const int lane = tid & 63;
    const int quad = lane >> 4;
    const int ln   = lane & 15;
    const int wm   = wave >> 1;   // 0..1
    const int wn   = wave & 1;    // 0..1
    const int srow = tid >> 3;    // 0..31 staging row within call
    const int kc8  = (tid & 7) * 8;

    f32x4 acc[2][4];
#pragma unroll
    for (int a = 0; a < 2; ++a)
#pragma unroll
        for (int b = 0; b < 4; ++b) acc[a][b] = (f32x4){0, 0, 0, 0};

    const int jend = i0 + 64;
    for (int j0 = 0; j0 < jend; j0 += 64) {
        const int g = i0 - j0;   // >= 0, multiple of 64
        __syncthreads();
#pragma unroll
        for (int c = 0; c < 2; ++c) {   // A tile: 2 x 4KB
            int r = c * 32 + srow;
            int s = r & 7, q = r >> 3;
            const bf16_t* gp = R + (size_t)s * R_STRIDE + (R_O0 - g - 8 * q + kc8);
            load_lds16(gp, &sA[c * 2048 + tid * 8]);
        }
#pragma unroll
        for (int c = 0; c < 4; ++c) {   // B tile: 4 x 4KB
            const bf16_t* gp = Eb + (size_t)(n0 + c * 32 + srow) * L_SER + j0 + kc8;
            load_lds16(gp, &sB[c * 2048 + tid * 8]);
        }
        __syncthreads();

#pragma unroll
        for (int kk = 0; kk < 2; ++kk) {
            bf16x8 afr[2], bfr[4];
#pragma unroll
            for (int tm = 0; tm < 2; ++tm)
                afr[tm] = *(const bf16x8*)&sA[(wm * 32 + tm * 16 + ln) * 64 + kk * 32 + quad * 8];
#pragma unroll
            for (int tn = 0; tn < 4; ++tn)
                bfr[tn] = *(const bf16x8*)&sB[(wn * 64 + tn * 16 + ln) * 64 + kk * 32 + quad * 8];
#pragma unroll
            for (int tm = 0; tm < 2; ++tm)
#pragma unroll
                for (int tn = 0; tn < 4; ++tn)
                    acc[tm][tn] = __builtin_amdgcn_mfma_f32_16x16x32_bf16(afr[tm], bfr[tn], acc[tm][tn], 0, 0, 0);
        }
    }

    // C/D: col = ln (n), row = quad*4 + r (m)
#pragma unroll
    for (int tm = 0; tm < 2; ++tm) {
        int row_base = i0 + wm * 32 + tm * 16 + quad * 4;
#pragma unroll
        for (int tn = 0; tn < 4; ++tn) {
            int col = n0 + wn * 64 + tn * 16 + ln;
#pragma unroll
            for (int r = 0; r < 4; ++r)
                T[(size_t)(row_base + r) * DEMB + col] = (bf16_t)acc[tm][tn][r];
        }
    }
}

// ---------------------------------------------------------------------------
// gemm_b: out[i,v] = sum_e T[i,e] W[v,e].  BM=128, BN=128, BK=64, K=1024.
// 4 waves as 2x2; each wave 64x64 = 4x4 MFMA tiles; 32 MFMA / K-step.
// ---------------------------------------------------------------------------
__global__ __launch_bounds__(256) void gemm_b_kernel(const bf16_t* __restrict__ T,
                                                     const bf16_t* __restrict__ Wb,
                                                     float* __restrict__ out) {
    __shared__ __align__(16) bf16_t sA[128 * 64];   // 16 KB
    __shared__ __align__(16) bf16_t sB[128 * 64];   // 16 KB

    const int i0 = blockIdx.y * 128;
    const int n0 = blockIdx.x * 128;

    const int tid  = threadIdx.x;
    const int wave = tid >> 6;
    const int lane = tid & 63;
    const int quad = lane >> 4;
    const int ln   = lane & 15;
    const int wm   = wave >> 1;
    const int wn   = wave & 1;
    const int srow = tid >> 3;
    const int kc8  = (tid & 7) * 8;

    f32x4 acc[4][4];
#pragma unroll
    for (int a = 0; a < 4; ++a)
#pragma unroll
        for (int b = 0; b < 4; ++b) acc[a][b] = (f32x4){0, 0, 0, 0};

    for (int e0 = 0; e0 < DEMB; e0 += 64) {
        __syncthreads();
#pragma unroll
        for (int c = 0; c < 4; ++c) {
            const bf16_t* gp = T + (size_t)(i0 + c * 32 + srow) * DEMB + e0 + kc8;
            load_lds16(gp, &sA[c * 2048 + tid * 8]);
        }
#pragma unroll
        for (int c = 0; c < 4; ++c) {
            const bf16_t* gp = Wb + (size_t)(n0 + c * 32 + srow) * DEMB + e0 + kc8;
            load_lds16(gp, &sB[c * 2048 + tid * 8]);
        }
        __syncthreads();

#pragma unroll
        for (int kk = 0; kk < 2; ++kk) {
            bf16x8 afr[4], bfr[4];
#pragma unroll
            for (int tm = 0; tm < 4; ++tm)
                afr[tm] = *(const bf16x8*)&sA[(wm * 64 + tm * 16 + ln) * 64 + kk * 32 + quad * 8];
#pragma unroll
            for (int tn = 0; tn < 4; ++tn)
                bfr[tn] = *(const bf16x8*)&sB[(wn * 64 + tn * 16 + ln) * 64 + kk * 32 + quad * 8];
#pragma unroll
            for (int tm = 0; tm < 4; ++tm)
#pragma unroll
                for (int tn = 0; tn < 4; ++tn)
                    acc[tm][tn] = __builtin_amdgcn_mfma_f32_16x16x32_bf16(afr[tm], bfr[tn], acc[tm][tn], 0, 0, 0);
        }
    }

#pragma unroll
    for (int tm = 0; tm < 4; ++tm) {
        int row_base = i0 + wm * 64 + tm * 16 + quad * 4;
#pragma unroll
        for (int tn = 0; tn < 4; ++tn) {
            int col = n0 + wn * 64 + tn * 16 + ln;
#pragma unroll
            for (int r = 0; r < 4; ++r)
                out[(size_t)(row_base + r) * DV + col] = acc[tm][tn][r];
        }
    }
}

// ---------------------------------------------------------------------------
extern "C" void kernel_launch(void* const* d_in, const int* in_sizes, int n_in,
                              void* d_out, int out_size, void* d_ws, size_t ws_size,
                              hipStream_t stream) {
    const float* E = (const float*)d_in[0];   // (1024, 4096) f32, l contiguous
    const float* W = (const float*)d_in[1];   // (1024, 1024) f32, e contiguous
    float* out = (float*)d_out;               // (4096, 1024) f32

    char* ws = (char*)d_ws;
    bf16_t* Eb = (bf16_t*)(ws);                               // 8 MB
    bf16_t* Tm = (bf16_t*)(ws + (size_t)8  * 1024 * 1024);    // 8 MB
    bf16_t* Wb = (bf16_t*)(ws + (size_t)16 * 1024 * 1024);    // 2 MB
    bf16_t* R  = (bf16_t*)(ws + (size_t)18 * 1024 * 1024);    // 65 KB

    build_r_kernel<<<(8 * R_STRIDE + 255) / 256, 256, 0, stream>>>(R);
    convert_kernel<<<(DEMB * L_SER / 8 + 255) / 256, 256, 0, stream>>>(E, Eb, DEMB * L_SER / 8);
    convert_kernel<<<(DV * DEMB / 8 + 255) / 256, 256, 0, stream>>>(W, Wb, DV * DEMB / 8);

    gemm_a_kernel<<<512, 256, 0, stream>>>(R, Eb, Tm);
    gemm_b_kernel<<<dim3(DV / 128, L_SER / 128), 256, 0, stream>>>(Tm, Wb, out);
}

// Round 3
// 134.848 us; speedup vs baseline: 1.6521x; 1.2079x over previous
//
#include <hip/hip_runtime.h>
#include <hip/hip_bf16.h>
#include <cstdint>
#include <cstddef>

// out = A2 @ (E^T @ W^T)  reassociated as  (A2 @ E^T) @ W^T
//   A2[i,j] = a[i-j] (lower-tri Toeplitz), a[d] = (d*dt+1e-8)^0.2, a[0]=1e-8^0.2
//   gemm_a: T[i,e] = sum_{j<=i} a[i-j] * E[e,j]   (M=4096, N=1024, K tri)
//   gemm_b: out[i,v] = sum_e T[i,e] * W[v,e]      (M=4096, N=1024, K=1024)
// Round 3: register-prefetch software pipeline (global->VGPR->LDS ping-pong,
// one barrier per K-step), padded LDS rows (72 elems) for bank uniformity.

#define L_SER 4096
#define DEMB  1024
#define DV    1024

#define R_STRIDE 4160   // elements per shift-replica of reversed a (16B-aligned)
#define R_O0     4096
#define LDP 72          // padded LDS row length (elements)

typedef __bf16 bf16_t;
typedef __attribute__((ext_vector_type(8))) __bf16 bf16x8;
typedef __attribute__((ext_vector_type(4))) float f32x4;

// ---------------------------------------------------------------------------
// R[s][x] = a_val(4096 + s - x): every Toeplitz A-tile row as aligned 16B load.
// ---------------------------------------------------------------------------
__global__ void build_r_kernel(bf16_t* __restrict__ R) {
    int idx = blockIdx.x * blockDim.x + threadIdx.x;
    if (idx >= 8 * R_STRIDE) return;
    int s = idx / R_STRIDE;
    int x = idx - s * R_STRIDE;
    int d = R_O0 + s - x;
    float v = 0.0f;
    if (d >= 0 && d < L_SER)
        v = powf((d == 0) ? 1e-8f : ((float)d * (1.0f / (float)L_SER) + 1e-8f), 0.2f);
    R[idx] = (bf16_t)v;
}

__global__ void convert_kernel(const float* __restrict__ src, bf16_t* __restrict__ dst, int n8) {
    int idx = blockIdx.x * blockDim.x + threadIdx.x;
    if (idx >= n8) return;
    const f32x4* s = (const f32x4*)src;
    f32x4 v0 = s[idx * 2], v1 = s[idx * 2 + 1];
    bf16x8 o;
    o[0] = (bf16_t)v0[0]; o[1] = (bf16_t)v0[1]; o[2] = (bf16_t)v0[2]; o[3] = (bf16_t)v0[3];
    o[4] = (bf16_t)v1[0]; o[5] = (bf16_t)v1[1]; o[6] = (bf16_t)v1[2]; o[7] = (bf16_t)v1[3];
    ((bf16x8*)dst)[idx] = o;
}

// ---------------------------------------------------------------------------
// gemm_a: T[i,e] = sum_j a[i-j] E[e,j].  BM=64, BN=128, BK=64, triangular K.
// 4 waves 2x2; wave tile 32m x 64n = 2x4 MFMA tiles; 16 MFMA / wave / K-step.
// ---------------------------------------------------------------------------
__global__ __launch_bounds__(256) void gemm_a_kernel(const bf16_t* __restrict__ R,
                                                     const bf16_t* __restrict__ Eb,
                                                     bf16_t* __restrict__ T) {
    __shared__ __align__(16) bf16_t sA[2][64 * LDP];    // 18 KB
    __shared__ __align__(16) bf16_t sB[2][128 * LDP];   // 36 KB

    const int bid   = blockIdx.x;
    const int i_blk = 63 - (bid >> 3);      // LPT: biggest-K blocks first
    const int n_blk = bid & 7;
    const int i0 = i_blk * 64;
    const int n0 = n_blk * 128;

    const int tid  = threadIdx.x;
    const int wave = tid >> 6;
    const int lane = tid & 63;
    const int quad = lane >> 4;
    const int ln   = lane & 15;
    const int wm   = wave >> 1;
    const int wn   = wave & 1;
    const int srow = tid >> 3;              // 0..31
    const int kc8  = (tid & 7) * 8;

    f32x4 acc[2][4];
#pragma unroll
    for (int a = 0; a < 2; ++a)
#pragma unroll
        for (int b = 0; b < 4; ++b) acc[a][b] = (f32x4){0, 0, 0, 0};

    const int nsteps = i_blk + 1;

    // A-row source precompute: row r -> replica s=r&7, back-offset 8*(r>>3)
    // x(step) = R_O0 - (i0 - 64*step) - 8*(r>>3) + kc8
    bf16x8 ra[2], rb[4];
#pragma unroll
    for (int c = 0; c < 2; ++c) {
        int r = c * 32 + srow;
        ra[c] = *(const bf16x8*)(R + (size_t)(r & 7) * R_STRIDE + (R_O0 - i0 - 8 * (r >> 3) + kc8));
    }
#pragma unroll
    for (int c = 0; c < 4; ++c)
        rb[c] = *(const bf16x8*)(Eb + (size_t)(n0 + c * 32 + srow) * L_SER + kc8);

    for (int step = 0; step < nsteps; ++step) {
        const int buf = step & 1;
#pragma unroll
        for (int c = 0; c < 2; ++c)
            *(bf16x8*)&sA[buf][(c * 32 + srow) * LDP + kc8] = ra[c];
#pragma unroll
        for (int c = 0; c < 4; ++c)
            *(bf16x8*)&sB[buf][(c * 32 + srow) * LDP + kc8] = rb[c];
        __syncthreads();

        if (step + 1 < nsteps) {
            const int j0n = (step + 1) * 64;
#pragma unroll
            for (int c = 0; c < 2; ++c) {
                int r = c * 32 + srow;
                ra[c] = *(const bf16x8*)(R + (size_t)(r & 7) * R_STRIDE +
                                         (R_O0 - i0 + j0n - 8 * (r >> 3) + kc8));
            }
#pragma unroll
            for (int c = 0; c < 4; ++c)
                rb[c] = *(const bf16x8*)(Eb + (size_t)(n0 + c * 32 + srow) * L_SER + j0n + kc8);
        }

#pragma unroll
        for (int kk = 0; kk < 2; ++kk) {
            bf16x8 afr[2], bfr[4];
#pragma unroll
            for (int tm = 0; tm < 2; ++tm)
                afr[tm] = *(const bf16x8*)&sA[buf][(wm * 32 + tm * 16 + ln) * LDP + kk * 32 + quad * 8];
#pragma unroll
            for (int tn = 0; tn < 4; ++tn)
                bfr[tn] = *(const bf16x8*)&sB[buf][(wn * 64 + tn * 16 + ln) * LDP + kk * 32 + quad * 8];
#pragma unroll
            for (int tm = 0; tm < 2; ++tm)
#pragma unroll
                for (int tn = 0; tn < 4; ++tn)
                    acc[tm][tn] = __builtin_amdgcn_mfma_f32_16x16x32_bf16(afr[tm], bfr[tn], acc[tm][tn], 0, 0, 0);
        }
    }

    // C/D: col = ln (n), row = quad*4 + r (m)
#pragma unroll
    for (int tm = 0; tm < 2; ++tm) {
        int row_base = i0 + wm * 32 + tm * 16 + quad * 4;
#pragma unroll
        for (int tn = 0; tn < 4; ++tn) {
            int col = n0 + wn * 64 + tn * 16 + ln;
#pragma unroll
            for (int r = 0; r < 4; ++r)
                T[(size_t)(row_base + r) * DEMB + col] = (bf16_t)acc[tm][tn][r];
        }
    }
}

// ---------------------------------------------------------------------------
// gemm_b: out[i,v] = sum_e T[i,e] W[v,e].  BM=64, BN=64, BK=64, K=1024.
// 1024 blocks -> 4 blocks/CU, 16 waves/CU. 4 waves 2x2; wave tile 32x32.
// ---------------------------------------------------------------------------
__global__ __launch_bounds__(256) void gemm_b_kernel(const bf16_t* __restrict__ T,
                                                     const bf16_t* __restrict__ Wb,
                                                     float* __restrict__ out) {
    __shared__ __align__(16) bf16_t sA[2][64 * LDP];   // 18 KB
    __shared__ __align__(16) bf16_t sB[2][64 * LDP];   // 18 KB

    const int i0 = blockIdx.y * 64;
    const int n0 = blockIdx.x * 64;

    const int tid  = threadIdx.x;
    const int wave = tid >> 6;
    const int lane = tid & 63;
    const int quad = lane >> 4;
    const int ln   = lane & 15;
    const int wm   = wave >> 1;
    const int wn   = wave & 1;
    const int srow = tid >> 3;
    const int kc8  = (tid & 7) * 8;

    f32x4 acc[2][2];
#pragma unroll
    for (int a = 0; a < 2; ++a)
#pragma unroll
        for (int b = 0; b < 2; ++b) acc[a][b] = (f32x4){0, 0, 0, 0};

    const int nsteps = DEMB / 64;   // 16

    bf16x8 ra[2], rb[2];
#pragma unroll
    for (int c = 0; c < 2; ++c) {
        ra[c] = *(const bf16x8*)(T  + (size_t)(i0 + c * 32 + srow) * DEMB + kc8);
        rb[c] = *(const bf16x8*)(Wb + (size_t)(n0 + c * 32 + srow) * DEMB + kc8);
    }

    for (int step = 0; step < nsteps; ++step) {
        const int buf = step & 1;
#pragma unroll
        for (int c = 0; c < 2; ++c) {
            *(bf16x8*)&sA[buf][(c * 32 + srow) * LDP + kc8] = ra[c];
            *(bf16x8*)&sB[buf][(c * 32 + srow) * LDP + kc8] = rb[c];
        }
        __syncthreads();

        if (step + 1 < nsteps) {
            const int e0n = (step + 1) * 64;
#pragma unroll
            for (int c = 0; c < 2; ++c) {
                ra[c] = *(const bf16x8*)(T  + (size_t)(i0 + c * 32 + srow) * DEMB + e0n + kc8);
                rb[c] = *(const bf16x8*)(Wb + (size_t)(n0 + c * 32 + srow) * DEMB + e0n + kc8);
            }
        }

#pragma unroll
        for (int kk = 0; kk < 2; ++kk) {
            bf16x8 afr[2], bfr[2];
#pragma unroll
            for (int tm = 0; tm < 2; ++tm)
                afr[tm] = *(const bf16x8*)&sA[buf][(wm * 32 + tm * 16 + ln) * LDP + kk * 32 + quad * 8];
#pragma unroll
            for (int tn = 0; tn < 2; ++tn)
                bfr[tn] = *(const bf16x8*)&sB[buf][(wn * 32 + tn * 16 + ln) * LDP + kk * 32 + quad * 8];
#pragma unroll
            for (int tm = 0; tm < 2; ++tm)
#pragma unroll
                for (int tn = 0; tn < 2; ++tn)
                    acc[tm][tn] = __builtin_amdgcn_mfma_f32_16x16x32_bf16(afr[tm], bfr[tn], acc[tm][tn], 0, 0, 0);
        }
    }

#pragma unroll
    for (int tm = 0; tm < 2; ++tm) {
        int row_base = i0 + wm * 32 + tm * 16 + quad * 4;
#pragma unroll
        for (int tn = 0; tn < 2; ++tn) {
            int col = n0 + wn * 32 + tn * 16 + ln;
#pragma unroll
            for (int r = 0; r < 4; ++r)
                out[(size_t)(row_base + r) * DV + col] = acc[tm][tn][r];
        }
    }
}

// ---------------------------------------------------------------------------
extern "C" void kernel_launch(void* const* d_in, const int* in_sizes, int n_in,
                              void* d_out, int out_size, void* d_ws, size_t ws_size,
                              hipStream_t stream) {
    const float* E = (const float*)d_in[0];   // (1024, 4096) f32, l contiguous
    const float* W = (const float*)d_in[1];   // (1024, 1024) f32, e contiguous
    float* out = (float*)d_out;               // (4096, 1024) f32

    char* ws = (char*)d_ws;
    bf16_t* Eb = (bf16_t*)(ws);                               // 8 MB
    bf16_t* Tm = (bf16_t*)(ws + (size_t)8  * 1024 * 1024);    // 8 MB
    bf16_t* Wb = (bf16_t*)(ws + (size_t)16 * 1024 * 1024);    // 2 MB
    bf16_t* R  = (bf16_t*)(ws + (size_t)18 * 1024 * 1024);    // 65 KB

    build_r_kernel<<<(8 * R_STRIDE + 255) / 256, 256, 0, stream>>>(R);
    convert_kernel<<<(DEMB * L_SER / 8 + 255) / 256, 256, 0, stream>>>(E, Eb, DEMB * L_SER / 8);
    convert_kernel<<<(DV * DEMB / 8 + 255) / 256, 256, 0, stream>>>(W, Wb, DV * DEMB / 8);

    gemm_a_kernel<<<512, 256, 0, stream>>>(R, Eb, Tm);
    gemm_b_kernel<<<dim3(DV / 64, L_SER / 64), 256, 0, stream>>>(Tm, Wb, out);
}